// Round 4
// baseline (234.950 us; speedup 1.0000x reference)
//
#include <hip/hip_runtime.h>
#include <hip/hip_bf16.h>

typedef __attribute__((ext_vector_type(8))) short short8;
typedef __attribute__((ext_vector_type(4))) short short4v;
typedef __attribute__((ext_vector_type(4))) float f32x4;

#define BB 2
#define LL 2048
#define DD 1024
#define HH 16
#define DHH 64
#define KK 1024

__device__ __forceinline__ void gload_lds16(const void* g, void* l) {
  __builtin_amdgcn_global_load_lds((const __attribute__((address_space(1))) void*)g,
                                   (__attribute__((address_space(3))) void*)l,
                                   16, 0, 0);
}

__device__ __forceinline__ f32x4 splat4(float x) {
  f32x4 v; v[0] = x; v[1] = x; v[2] = x; v[3] = x; return v;
}

__device__ __forceinline__ unsigned short f2b(float x) {
  __hip_bfloat16 h = __float2bfloat16(x);
  return *reinterpret_cast<unsigned short*>(&h);
}

// fp32 -> bf16 bulk convert, 8 elements/thread
__global__ void cvt_f32_bf16(const float* __restrict__ src,
                             __hip_bfloat16* __restrict__ dst, int n8) {
  int i = blockIdx.x * blockDim.x + threadIdx.x;
  if (i >= n8) return;
  const f32x4 a = ((const f32x4*)src)[i * 2];
  const f32x4 b = ((const f32x4*)src)[i * 2 + 1];
  short8 o;
#pragma unroll
  for (int j = 0; j < 4; ++j) o[j] = (short)f2b(a[j]);
#pragma unroll
  for (int j = 0; j < 4; ++j) o[4 + j] = (short)f2b(b[j]);
  ((short8*)dst)[i] = o;
}

// C = A @ B^T (+bias). A: MxK bf16 row-major, B: NxK bf16 row-major. K=1024.
// QKV mode scatters into Q/K (B,H,L,DH) and V TRANSPOSED (B,H,DH,L), bf16.
// Direct mode writes fp32 C[m*N+n].
template<bool QKV>
__global__ void gemm_bt(const __hip_bfloat16* __restrict__ A,
                        const __hip_bfloat16* __restrict__ Bm,
                        const float* __restrict__ bias,
                        __hip_bfloat16* __restrict__ Cq,
                        __hip_bfloat16* __restrict__ Ck,
                        __hip_bfloat16* __restrict__ Cv,
                        float* __restrict__ Cd,
                        int N, int nbn) {
  __shared__ __align__(16) char As[8192];
  __shared__ __align__(16) char Bs[8192];
  const int tid = threadIdx.x;
  const int lane = tid & 63, wid = tid >> 6;
  const int l15 = lane & 15, lhi = lane >> 4;
  const int wm = wid >> 1, wn = wid & 1;
  const int bn = blockIdx.x % nbn, bm = blockIdx.x / nbn;
  const int m0 = bm * 128, n0 = bn * 128;

  f32x4 acc[4][4] = {};

  for (int kt = 0; kt < KK / 32; ++kt) {
    const int k0 = kt * 32;
    __syncthreads();
#pragma unroll
    for (int j = 0; j < 2; ++j) {
      int c = wid * 128 + j * 64 + lane;       // 16B chunk index
      int row = c >> 2;
      int ab = ((c & 3) * 16) ^ (((row >> 1) & 3) << 4);
      gload_lds16(A + (size_t)(m0 + row) * KK + k0 + (ab >> 1),
                  As + wid * 2048 + j * 1024);
    }
#pragma unroll
    for (int j = 0; j < 2; ++j) {
      int c = wid * 128 + j * 64 + lane;
      int row = c >> 2;
      int ab = ((c & 3) * 16) ^ (((row >> 1) & 3) << 4);
      gload_lds16(Bm + (size_t)(n0 + row) * KK + k0 + (ab >> 1),
                  Bs + wid * 2048 + j * 1024);
    }
    __syncthreads();

    short8 af[4], bf[4];
#pragma unroll
    for (int mf = 0; mf < 4; ++mf) {
      int row = wm * 64 + mf * 16 + l15;
      int byt = (lhi * 16) ^ (((row >> 1) & 3) << 4);
      af[mf] = *(const short8*)(As + row * 64 + byt);
    }
#pragma unroll
    for (int nf = 0; nf < 4; ++nf) {
      int row = wn * 64 + nf * 16 + l15;
      int byt = (lhi * 16) ^ (((row >> 1) & 3) << 4);
      bf[nf] = *(const short8*)(Bs + row * 64 + byt);
    }
#pragma unroll
    for (int mf = 0; mf < 4; ++mf)
#pragma unroll
      for (int nf = 0; nf < 4; ++nf)
        acc[mf][nf] = __builtin_amdgcn_mfma_f32_16x16x32_bf16(af[mf], bf[nf],
                                                              acc[mf][nf], 0, 0, 0);
  }

  // epilogue: C/D layout col=lane&15, row=(lane>>4)*4+reg
#pragma unroll
  for (int mf = 0; mf < 4; ++mf) {
#pragma unroll
    for (int nf = 0; nf < 4; ++nf) {
      const int n = n0 + wn * 64 + nf * 16 + l15;
      if constexpr (QKV) {
        const int sect = n >> 10;          // 0=q 1=k 2=v
        const int nn = n & 1023;
        const int h = nn >> 6, dh = nn & 63;
        const float bv = bias[n];
        const int m_base = m0 + wm * 64 + mf * 16 + lhi * 4;   // +r, same 2k page
        const int b = m_base >> 11, ml = m_base & 2047;
        if (sect == 2) {
          // V transposed: [b*H+h][dh][l]; 4 r-values are l-contiguous -> 8B store
          short4v v;
#pragma unroll
          for (int r = 0; r < 4; ++r) v[r] = (short)f2b(acc[mf][nf][r] + bv);
          *(short4v*)&Cv[(((size_t)(b * HH + h)) * DHH + dh) * LL + ml] = v;
        } else {
          __hip_bfloat16* dst = (sect == 0) ? Cq : Ck;
#pragma unroll
          for (int r = 0; r < 4; ++r)
            dst[(((size_t)(b * HH + h)) * LL + ml + r) * DHH + dh] =
                __float2bfloat16(acc[mf][nf][r] + bv);
        }
      } else {
#pragma unroll
        for (int r = 0; r < 4; ++r) {
          const int m = m0 + wm * 64 + mf * 16 + lhi * 4 + r;
          Cd[(size_t)m * N + n] = acc[mf][nf][r];
        }
      }
    }
  }
}

// stage one 64-kv tile: K rows [kv][128B] + V^T rows [dh][128B], XOR-swizzled src
__device__ __forceinline__ void stage_tile(const __hip_bfloat16* __restrict__ Kg,
                                           const __hip_bfloat16* __restrict__ VTg,
                                           char* KsB, char* VsB, int kv0, int tid) {
  const int lane = tid & 63, wid = tid >> 6;
#pragma unroll
  for (int j = 0; j < 2; ++j) {
    int c = wid * 128 + j * 64 + lane;
    int kv = c >> 3;
    int ab = ((c & 7) * 16) ^ ((kv & 7) << 4);
    gload_lds16(Kg + (size_t)(kv0 + kv) * DHH + (ab >> 1), KsB + wid * 2048 + j * 1024);
  }
#pragma unroll
  for (int j = 0; j < 2; ++j) {
    int c = wid * 128 + j * 64 + lane;
    int dh = c >> 3;
    int ab = ((c & 7) * 16) ^ ((dh & 7) << 4);
    gload_lds16(VTg + (size_t)dh * LL + kv0 + (ab >> 1), VsB + wid * 2048 + j * 1024);
  }
}

// Flash attention: 256 blocks = 8 qt-pairs x 32 bh. Block runs two passes
// (qt, 15-qt): uniform 34 tiles causal. 4 waves x 32 q-rows, KV tiles of 64.
__global__ void attn_fwd(const __hip_bfloat16* __restrict__ Q,
                         const __hip_bfloat16* __restrict__ K,
                         const __hip_bfloat16* __restrict__ VT,
                         __hip_bfloat16* __restrict__ att,
                         const int* __restrict__ maskp) {
  __shared__ __align__(16) char Ks[2][8192];   // [kv64][128B], byte^=(kv&7)<<4
  __shared__ __align__(16) char Vs[2][8192];   // [dh64][128B], byte^=(dh&7)<<4
  __shared__ __align__(16) char Ps[4][4096];   // per-wave [row32][128B], byte^=((row>>2)&3)<<5
  const int tid = threadIdx.x;
  const int lane = tid & 63, wid = tid >> 6;
  const int l15 = lane & 15, lhi = lane >> 4;
  const int bid = blockIdx.x;
  const int pair = bid >> 5;        // 0..7
  const int bh = bid & 31;
  const int causal = *maskp;
  const __hip_bfloat16* Qg = Q + (size_t)bh * LL * DHH;
  const __hip_bfloat16* Kg = K + (size_t)bh * LL * DHH;
  const __hip_bfloat16* VTg = VT + (size_t)bh * DHH * LL;
  char* Pw = Ps[wid];

  for (int pass = 0; pass < 2; ++pass) {
    const int qt = pass ? pair : (15 - pair);
    const int r0 = qt * 128 + wid * 32;

    // Q fragments in registers for the whole pass
    short8 aq[2][2];
#pragma unroll
    for (int mf = 0; mf < 2; ++mf)
#pragma unroll
      for (int ks = 0; ks < 2; ++ks)
        aq[mf][ks] = *(const short8*)(Qg + (size_t)(r0 + mf * 16 + l15) * DHH +
                                      ks * 32 + lhi * 8);

    f32x4 o[2][4] = {};
    f32x4 mrun[2], lrun[2];
    mrun[0] = splat4(-1e30f); mrun[1] = splat4(-1e30f);
    lrun[0] = splat4(0.0f);   lrun[1] = splat4(0.0f);

    const int nt = causal ? (qt + 1) * 2 : (LL / 64);
    __syncthreads();                       // LDS reuse across passes
    stage_tile(Kg, VTg, Ks[0], Vs[0], 0, tid);
    int cur = 0;

    for (int t = 0; t < nt; ++t) {
      __syncthreads();                     // buf[cur] staged; prev reads done
      if (t + 1 < nt)
        stage_tile(Kg, VTg, Ks[cur ^ 1], Vs[cur ^ 1], (t + 1) * 64, tid);
      const int kv0 = t * 64;

      if (!causal || kv0 <= r0 + 31) {
        // QK^T
        short8 bk[4][2];
#pragma unroll
        for (int nf = 0; nf < 4; ++nf) {
          int kv = nf * 16 + l15;
#pragma unroll
          for (int ks = 0; ks < 2; ++ks) {
            int byt = (ks * 64 + lhi * 16) ^ ((kv & 7) << 4);
            bk[nf][ks] = *(const short8*)(Ks[cur] + kv * 128 + byt);
          }
        }
        f32x4 s[2][4] = {};
#pragma unroll
        for (int mf = 0; mf < 2; ++mf)
#pragma unroll
          for (int nf = 0; nf < 4; ++nf) {
            s[mf][nf] = __builtin_amdgcn_mfma_f32_16x16x32_bf16(aq[mf][0], bk[nf][0], s[mf][nf], 0, 0, 0);
            s[mf][nf] = __builtin_amdgcn_mfma_f32_16x16x32_bf16(aq[mf][1], bk[nf][1], s[mf][nf], 0, 0, 0);
          }
        // scale + causal mask
        const bool needmask = causal && (kv0 + 63 > r0);
#pragma unroll
        for (int mf = 0; mf < 2; ++mf)
#pragma unroll
          for (int nf = 0; nf < 4; ++nf) {
            const int kv = kv0 + nf * 16 + l15;
#pragma unroll
            for (int r = 0; r < 4; ++r) {
              float v = s[mf][nf][r] * 0.125f;   // 1/sqrt(64)
              if (needmask && kv > r0 + mf * 16 + lhi * 4 + r) v = -1e30f;
              s[mf][nf][r] = v;
            }
          }
        // online softmax
#pragma unroll
        for (int mf = 0; mf < 2; ++mf) {
          f32x4 pm = s[mf][0];
#pragma unroll
          for (int nf = 1; nf < 4; ++nf)
#pragma unroll
            for (int r = 0; r < 4; ++r) pm[r] = fmaxf(pm[r], s[mf][nf][r]);
#pragma unroll
          for (int d = 1; d < 16; d <<= 1)
#pragma unroll
            for (int r = 0; r < 4; ++r) pm[r] = fmaxf(pm[r], __shfl_xor(pm[r], d, 64));

          f32x4 mnew, rsum;
#pragma unroll
          for (int r = 0; r < 4; ++r) {
            mnew[r] = fmaxf(mrun[mf][r], pm[r]);
            float sc = __expf(mrun[mf][r] - mnew[r]);
            lrun[mf][r] *= sc;
            rsum[r] = 0.0f;
#pragma unroll
            for (int nf = 0; nf < 4; ++nf) o[mf][nf][r] *= sc;
          }
#pragma unroll
          for (int nf = 0; nf < 4; ++nf)
#pragma unroll
            for (int r = 0; r < 4; ++r) {
              float p = __expf(s[mf][nf][r] - mnew[r]);
              s[mf][nf][r] = p;
              rsum[r] += p;
            }
#pragma unroll
          for (int d = 1; d < 16; d <<= 1)
#pragma unroll
            for (int r = 0; r < 4; ++r) rsum[r] += __shfl_xor(rsum[r], d, 64);
#pragma unroll
          for (int r = 0; r < 4; ++r) lrun[mf][r] += rsum[r];
          mrun[mf] = mnew;
        }
        // P -> per-wave LDS (swizzled: byte ^= ((row>>2)&3)<<5)
#pragma unroll
        for (int mf = 0; mf < 2; ++mf)
#pragma unroll
          for (int nf = 0; nf < 4; ++nf)
#pragma unroll
            for (int r = 0; r < 4; ++r) {
              const int row = mf * 16 + lhi * 4 + r;
              const int cb = (nf * 16 + l15) * 2;
              *(__hip_bfloat16*)(Pw + row * 128 + (cb ^ ((row & 12) << 3))) =
                  __float2bfloat16(s[mf][nf][r]);
            }
        // PV
        short8 ap[2][2];
#pragma unroll
        for (int mf = 0; mf < 2; ++mf)
#pragma unroll
          for (int ks = 0; ks < 2; ++ks) {
            const int row = mf * 16 + l15;
            const int cb = ks * 64 + lhi * 16;
            ap[mf][ks] = *(const short8*)(Pw + row * 128 + (cb ^ ((row & 12) << 3)));
          }
        short8 bv[4][2];
#pragma unroll
        for (int nf = 0; nf < 4; ++nf)
#pragma unroll
          for (int ks = 0; ks < 2; ++ks) {
            const int dh = nf * 16 + l15;
            const int byt = (ks * 64 + lhi * 16) ^ ((dh & 7) << 4);
            bv[nf][ks] = *(const short8*)(Vs[cur] + dh * 128 + byt);
          }
#pragma unroll
        for (int mf = 0; mf < 2; ++mf)
#pragma unroll
          for (int nf = 0; nf < 4; ++nf) {
            o[mf][nf] = __builtin_amdgcn_mfma_f32_16x16x32_bf16(ap[mf][0], bv[nf][0], o[mf][nf], 0, 0, 0);
            o[mf][nf] = __builtin_amdgcn_mfma_f32_16x16x32_bf16(ap[mf][1], bv[nf][1], o[mf][nf], 0, 0, 0);
          }
      }
      cur ^= 1;
    }

    // finalize: att layout (B, L, H*DH) merged heads
    const int b = bh >> 4, h = bh & 15;
#pragma unroll
    for (int mf = 0; mf < 2; ++mf)
#pragma unroll
      for (int r = 0; r < 4; ++r) {
        const int row = r0 + mf * 16 + lhi * 4 + r;
        const float inv = 1.0f / lrun[mf][r];
#pragma unroll
        for (int nf = 0; nf < 4; ++nf)
          att[((size_t)(b * LL + row)) * DD + h * DHH + nf * 16 + l15] =
              __float2bfloat16(o[mf][nf][r] * inv);
      }
  }
}

extern "C" void kernel_launch(void* const* d_in, const int* in_sizes, int n_in,
                              void* d_out, int out_size, void* d_ws, size_t ws_size,
                              hipStream_t stream) {
  const float* x     = (const float*)d_in[0];
  const float* w_in  = (const float*)d_in[1];
  const float* b_in  = (const float*)d_in[2];
  const float* w_out = (const float*)d_in[3];
  const int* mask    = (const int*)d_in[4];
  float* out = (float*)d_out;

  char* ws = (char*)d_ws;
  const size_t MiB = 1024u * 1024u;
  __hip_bfloat16* xb    = (__hip_bfloat16*)(ws);             // 8 MiB
  __hip_bfloat16* w_inb = (__hip_bfloat16*)(ws + 8 * MiB);   // 6 MiB
  __hip_bfloat16* w_outb= (__hip_bfloat16*)(ws + 14 * MiB);  // 2 MiB
  __hip_bfloat16* Qb    = (__hip_bfloat16*)(ws + 16 * MiB);  // 8 MiB
  __hip_bfloat16* Kb    = (__hip_bfloat16*)(ws + 24 * MiB);  // 8 MiB
  __hip_bfloat16* Vtb   = (__hip_bfloat16*)(ws + 32 * MiB);  // 8 MiB (transposed)
  __hip_bfloat16* att   = (__hip_bfloat16*)(ws + 40 * MiB);  // 8 MiB

  cvt_f32_bf16<<<dim3((BB * LL * DD) / 8 / 256), dim3(256), 0, stream>>>(x, xb, (BB * LL * DD) / 8);
  cvt_f32_bf16<<<dim3((3 * DD * DD) / 8 / 256), dim3(256), 0, stream>>>(w_in, w_inb, (3 * DD * DD) / 8);
  cvt_f32_bf16<<<dim3((DD * DD) / 8 / 256), dim3(256), 0, stream>>>(w_out, w_outb, (DD * DD) / 8);

  gemm_bt<true><<<dim3(32 * 24), dim3(256), 0, stream>>>(
      xb, w_inb, b_in, Qb, Kb, Vtb, nullptr, 3072, 24);
  attn_fwd<<<dim3(256), dim3(256), 0, stream>>>(Qb, Kb, Vtb, att, mask);
  gemm_bt<false><<<dim3(32 * 8), dim3(256), 0, stream>>>(
      att, w_outb, nullptr, nullptr, nullptr, nullptr, out, 1024, 8);
}

// Round 5
// 162.908 us; speedup vs baseline: 1.4422x; 1.4422x over previous
//
#include <hip/hip_runtime.h>
#include <hip/hip_bf16.h>

typedef __attribute__((ext_vector_type(8))) short short8;
typedef __attribute__((ext_vector_type(4))) short short4v;
typedef __attribute__((ext_vector_type(4))) float f32x4;

#define BB 2
#define LL 2048
#define DD 1024
#define HH 16
#define DHH 64
#define KK 1024

__device__ __forceinline__ void gload_lds16(const void* g, void* l) {
  __builtin_amdgcn_global_load_lds((const __attribute__((address_space(1))) void*)g,
                                   (__attribute__((address_space(3))) void*)l,
                                   16, 0, 0);
}

__device__ __forceinline__ f32x4 splat4(float x) {
  f32x4 v; v[0] = x; v[1] = x; v[2] = x; v[3] = x; return v;
}

__device__ __forceinline__ unsigned short f2b(float x) {
  __hip_bfloat16 h = __float2bfloat16(x);
  return *reinterpret_cast<unsigned short*>(&h);
}

// fp32 -> bf16 bulk convert, 8 elements/thread
__global__ void cvt_f32_bf16(const float* __restrict__ src,
                             __hip_bfloat16* __restrict__ dst, int n8) {
  int i = blockIdx.x * blockDim.x + threadIdx.x;
  if (i >= n8) return;
  const f32x4 a = ((const f32x4*)src)[i * 2];
  const f32x4 b = ((const f32x4*)src)[i * 2 + 1];
  short8 o;
#pragma unroll
  for (int j = 0; j < 4; ++j) o[j] = (short)f2b(a[j]);
#pragma unroll
  for (int j = 0; j < 4; ++j) o[4 + j] = (short)f2b(b[j]);
  ((short8*)dst)[i] = o;
}

// C = A @ B^T (+bias). A: MxK bf16 row-major, B: NxK bf16 row-major. K=1024.
// QKV mode scatters into Q/K (B,H,L,DH) and V TRANSPOSED (B,H,DH,L), bf16.
// Direct mode writes fp32 C[m*N+n].
template<bool QKV>
__global__ void gemm_bt(const __hip_bfloat16* __restrict__ A,
                        const __hip_bfloat16* __restrict__ Bm,
                        const float* __restrict__ bias,
                        __hip_bfloat16* __restrict__ Cq,
                        __hip_bfloat16* __restrict__ Ck,
                        __hip_bfloat16* __restrict__ Cv,
                        float* __restrict__ Cd,
                        int N, int nbn) {
  __shared__ __align__(16) char As[8192];
  __shared__ __align__(16) char Bs[8192];
  const int tid = threadIdx.x;
  const int lane = tid & 63, wid = tid >> 6;
  const int l15 = lane & 15, lhi = lane >> 4;
  const int wm = wid >> 1, wn = wid & 1;
  const int bn = blockIdx.x % nbn, bm = blockIdx.x / nbn;
  const int m0 = bm * 128, n0 = bn * 128;

  f32x4 acc[4][4] = {};

  for (int kt = 0; kt < KK / 32; ++kt) {
    const int k0 = kt * 32;
    __syncthreads();
#pragma unroll
    for (int j = 0; j < 2; ++j) {
      int c = wid * 128 + j * 64 + lane;       // 16B chunk index
      int row = c >> 2;
      int ab = ((c & 3) * 16) ^ (((row >> 1) & 3) << 4);
      gload_lds16(A + (size_t)(m0 + row) * KK + k0 + (ab >> 1),
                  As + wid * 2048 + j * 1024);
    }
#pragma unroll
    for (int j = 0; j < 2; ++j) {
      int c = wid * 128 + j * 64 + lane;
      int row = c >> 2;
      int ab = ((c & 3) * 16) ^ (((row >> 1) & 3) << 4);
      gload_lds16(Bm + (size_t)(n0 + row) * KK + k0 + (ab >> 1),
                  Bs + wid * 2048 + j * 1024);
    }
    __syncthreads();

    short8 af[4], bf[4];
#pragma unroll
    for (int mf = 0; mf < 4; ++mf) {
      int row = wm * 64 + mf * 16 + l15;
      int byt = (lhi * 16) ^ (((row >> 1) & 3) << 4);
      af[mf] = *(const short8*)(As + row * 64 + byt);
    }
#pragma unroll
    for (int nf = 0; nf < 4; ++nf) {
      int row = wn * 64 + nf * 16 + l15;
      int byt = (lhi * 16) ^ (((row >> 1) & 3) << 4);
      bf[nf] = *(const short8*)(Bs + row * 64 + byt);
    }
#pragma unroll
    for (int mf = 0; mf < 4; ++mf)
#pragma unroll
      for (int nf = 0; nf < 4; ++nf)
        acc[mf][nf] = __builtin_amdgcn_mfma_f32_16x16x32_bf16(af[mf], bf[nf],
                                                              acc[mf][nf], 0, 0, 0);
  }

  // epilogue: C/D layout col=lane&15, row=(lane>>4)*4+reg
#pragma unroll
  for (int mf = 0; mf < 4; ++mf) {
#pragma unroll
    for (int nf = 0; nf < 4; ++nf) {
      const int n = n0 + wn * 64 + nf * 16 + l15;
      if constexpr (QKV) {
        const int sect = n >> 10;          // 0=q 1=k 2=v
        const int nn = n & 1023;
        const int h = nn >> 6, dh = nn & 63;
        const float bv = bias[n];
        const int m_base = m0 + wm * 64 + mf * 16 + lhi * 4;   // +r, same 2k page
        const int b = m_base >> 11, ml = m_base & 2047;
        if (sect == 2) {
          // V transposed: [b*H+h][dh][l]; 4 r-values are l-contiguous -> 8B store
          short4v v;
#pragma unroll
          for (int r = 0; r < 4; ++r) v[r] = (short)f2b(acc[mf][nf][r] + bv);
          *(short4v*)&Cv[(((size_t)(b * HH + h)) * DHH + dh) * LL + ml] = v;
        } else {
          __hip_bfloat16* dst = (sect == 0) ? Cq : Ck;
#pragma unroll
          for (int r = 0; r < 4; ++r)
            dst[(((size_t)(b * HH + h)) * LL + ml + r) * DHH + dh] =
                __float2bfloat16(acc[mf][nf][r] + bv);
        }
      } else {
#pragma unroll
        for (int r = 0; r < 4; ++r) {
          const int m = m0 + wm * 64 + mf * 16 + lhi * 4 + r;
          Cd[(size_t)m * N + n] = acc[mf][nf][r];
        }
      }
    }
  }
}

// Flash attention: 2048 one-wave blocks. Block = 32 q-rows of one head.
// No barriers, no K/V LDS staging (L2-resident); P via 4KB wave-private LDS.
__global__ __launch_bounds__(64) void attn_fwd(
    const __hip_bfloat16* __restrict__ Q,
    const __hip_bfloat16* __restrict__ K,
    const __hip_bfloat16* __restrict__ VT,
    __hip_bfloat16* __restrict__ att,
    const int* __restrict__ maskp) {
  __shared__ __align__(16) char Pw[4096];   // [row32][128B], byte^=((row&12)<<3)
  const int lane = threadIdx.x;             // 0..63
  const int l15 = lane & 15, lhi = lane >> 4;
  const int bid = blockIdx.x;
  const int strip = 63 - (bid >> 5);        // heavy strips dispatched first
  const int bh = bid & 31;                  // head pinned to XCD bh%8
  const int causal = *maskp;
  const int r0 = strip * 32;
  const __hip_bfloat16* Qg = Q + (size_t)bh * LL * DHH;
  const __hip_bfloat16* Kg = K + (size_t)bh * LL * DHH;
  const __hip_bfloat16* VTg = VT + (size_t)bh * DHH * LL;

  // Q fragments in registers for the whole block
  short8 aq[2][2];
#pragma unroll
  for (int mf = 0; mf < 2; ++mf)
#pragma unroll
    for (int ks = 0; ks < 2; ++ks)
      aq[mf][ks] = *(const short8*)(Qg + (size_t)(r0 + mf * 16 + l15) * DHH +
                                    ks * 32 + lhi * 8);

  f32x4 o[2][4] = {};
  f32x4 mrun[2], lrun[2];
  mrun[0] = splat4(-1e30f); mrun[1] = splat4(-1e30f);
  lrun[0] = splat4(0.0f);   lrun[1] = splat4(0.0f);

  const int nt = causal ? ((r0 + 31) >> 6) + 1 : (LL / 64);

  for (int t = 0; t < nt; ++t) {
    const int kv0 = t * 64;
    // K fragments direct from global (B-operand: col=kv, k=dh)
    short8 bk[4][2];
#pragma unroll
    for (int nf = 0; nf < 4; ++nf)
#pragma unroll
      for (int ks = 0; ks < 2; ++ks)
        bk[nf][ks] = *(const short8*)(Kg + (size_t)(kv0 + nf * 16 + l15) * DHH +
                                      ks * 32 + lhi * 8);
    // V^T fragments issued early; consumed after softmax (latency hidden)
    short8 bv[4][2];
#pragma unroll
    for (int nf = 0; nf < 4; ++nf)
#pragma unroll
      for (int ks = 0; ks < 2; ++ks)
        bv[nf][ks] = *(const short8*)(VTg + (size_t)(nf * 16 + l15) * LL +
                                      kv0 + ks * 32 + lhi * 8);

    // QK^T
    f32x4 s[2][4] = {};
    __builtin_amdgcn_s_setprio(1);
#pragma unroll
    for (int mf = 0; mf < 2; ++mf)
#pragma unroll
      for (int nf = 0; nf < 4; ++nf) {
        s[mf][nf] = __builtin_amdgcn_mfma_f32_16x16x32_bf16(aq[mf][0], bk[nf][0], s[mf][nf], 0, 0, 0);
        s[mf][nf] = __builtin_amdgcn_mfma_f32_16x16x32_bf16(aq[mf][1], bk[nf][1], s[mf][nf], 0, 0, 0);
      }
    __builtin_amdgcn_s_setprio(0);

    // scale + causal mask
    const bool needmask = causal && (kv0 + 63 > r0);
#pragma unroll
    for (int mf = 0; mf < 2; ++mf)
#pragma unroll
      for (int nf = 0; nf < 4; ++nf) {
        const int kv = kv0 + nf * 16 + l15;
#pragma unroll
        for (int r = 0; r < 4; ++r) {
          float v = s[mf][nf][r] * 0.125f;   // 1/sqrt(64)
          if (needmask && kv > r0 + mf * 16 + lhi * 4 + r) v = -1e30f;
          s[mf][nf][r] = v;
        }
      }
    // online softmax
#pragma unroll
    for (int mf = 0; mf < 2; ++mf) {
      f32x4 pm = s[mf][0];
#pragma unroll
      for (int nf = 1; nf < 4; ++nf)
#pragma unroll
        for (int r = 0; r < 4; ++r) pm[r] = fmaxf(pm[r], s[mf][nf][r]);
#pragma unroll
      for (int d = 1; d < 16; d <<= 1)
#pragma unroll
        for (int r = 0; r < 4; ++r) pm[r] = fmaxf(pm[r], __shfl_xor(pm[r], d, 64));

      f32x4 mnew, rsum;
#pragma unroll
      for (int r = 0; r < 4; ++r) {
        mnew[r] = fmaxf(mrun[mf][r], pm[r]);
        float sc = __expf(mrun[mf][r] - mnew[r]);
        lrun[mf][r] *= sc;
        rsum[r] = 0.0f;
#pragma unroll
        for (int nf = 0; nf < 4; ++nf) o[mf][nf][r] *= sc;
      }
#pragma unroll
      for (int nf = 0; nf < 4; ++nf)
#pragma unroll
        for (int r = 0; r < 4; ++r) {
          float p = __expf(s[mf][nf][r] - mnew[r]);
          s[mf][nf][r] = p;
          rsum[r] += p;
        }
#pragma unroll
      for (int d = 1; d < 16; d <<= 1)
#pragma unroll
        for (int r = 0; r < 4; ++r) rsum[r] += __shfl_xor(rsum[r], d, 64);
#pragma unroll
      for (int r = 0; r < 4; ++r) lrun[mf][r] += rsum[r];
      mrun[mf] = mnew;
    }
    // P -> wave-private LDS (swizzled), then reload as PV A-operand
#pragma unroll
    for (int mf = 0; mf < 2; ++mf)
#pragma unroll
      for (int nf = 0; nf < 4; ++nf)
#pragma unroll
        for (int r = 0; r < 4; ++r) {
          const int row = mf * 16 + lhi * 4 + r;
          const int cb = (nf * 16 + l15) * 2;
          *(__hip_bfloat16*)(Pw + row * 128 + (cb ^ ((row & 12) << 3))) =
              __float2bfloat16(s[mf][nf][r]);
        }
    short8 ap[2][2];
#pragma unroll
    for (int mf = 0; mf < 2; ++mf)
#pragma unroll
      for (int ks = 0; ks < 2; ++ks) {
        const int row = mf * 16 + l15;
        const int cb = ks * 64 + lhi * 16;
        ap[mf][ks] = *(const short8*)(Pw + row * 128 + (cb ^ ((row & 12) << 3)));
      }
    // PV
    __builtin_amdgcn_s_setprio(1);
#pragma unroll
    for (int mf = 0; mf < 2; ++mf)
#pragma unroll
      for (int nf = 0; nf < 4; ++nf) {
        o[mf][nf] = __builtin_amdgcn_mfma_f32_16x16x32_bf16(ap[mf][0], bv[nf][0], o[mf][nf], 0, 0, 0);
        o[mf][nf] = __builtin_amdgcn_mfma_f32_16x16x32_bf16(ap[mf][1], bv[nf][1], o[mf][nf], 0, 0, 0);
      }
    __builtin_amdgcn_s_setprio(0);
  }

  // finalize: att layout (B, L, H*DH) merged heads
  const int b = bh >> 4, h = bh & 15;
#pragma unroll
  for (int mf = 0; mf < 2; ++mf)
#pragma unroll
    for (int r = 0; r < 4; ++r) {
      const int row = r0 + mf * 16 + lhi * 4 + r;
      const float inv = 1.0f / lrun[mf][r];
#pragma unroll
      for (int nf = 0; nf < 4; ++nf)
        att[((size_t)(b * LL + row)) * DD + h * DHH + nf * 16 + l15] =
            __float2bfloat16(o[mf][nf][r] * inv);
    }
}

extern "C" void kernel_launch(void* const* d_in, const int* in_sizes, int n_in,
                              void* d_out, int out_size, void* d_ws, size_t ws_size,
                              hipStream_t stream) {
  const float* x     = (const float*)d_in[0];
  const float* w_in  = (const float*)d_in[1];
  const float* b_in  = (const float*)d_in[2];
  const float* w_out = (const float*)d_in[3];
  const int* mask    = (const int*)d_in[4];
  float* out = (float*)d_out;

  char* ws = (char*)d_ws;
  const size_t MiB = 1024u * 1024u;
  __hip_bfloat16* xb    = (__hip_bfloat16*)(ws);             // 8 MiB
  __hip_bfloat16* w_inb = (__hip_bfloat16*)(ws + 8 * MiB);   // 6 MiB
  __hip_bfloat16* w_outb= (__hip_bfloat16*)(ws + 14 * MiB);  // 2 MiB
  __hip_bfloat16* Qb    = (__hip_bfloat16*)(ws + 16 * MiB);  // 8 MiB
  __hip_bfloat16* Kb    = (__hip_bfloat16*)(ws + 24 * MiB);  // 8 MiB
  __hip_bfloat16* Vtb   = (__hip_bfloat16*)(ws + 32 * MiB);  // 8 MiB (transposed)
  __hip_bfloat16* att   = (__hip_bfloat16*)(ws + 40 * MiB);  // 8 MiB

  cvt_f32_bf16<<<dim3((BB * LL * DD) / 8 / 256), dim3(256), 0, stream>>>(x, xb, (BB * LL * DD) / 8);
  cvt_f32_bf16<<<dim3((3 * DD * DD) / 8 / 256), dim3(256), 0, stream>>>(w_in, w_inb, (3 * DD * DD) / 8);
  cvt_f32_bf16<<<dim3((DD * DD) / 8 / 256), dim3(256), 0, stream>>>(w_out, w_outb, (DD * DD) / 8);

  gemm_bt<true><<<dim3(32 * 24), dim3(256), 0, stream>>>(
      xb, w_inb, b_in, Qb, Kb, Vtb, nullptr, 3072, 24);
  attn_fwd<<<dim3(2048), dim3(64), 0, stream>>>(Qb, Kb, Vtb, att, mask);
  gemm_bt<false><<<dim3(32 * 8), dim3(256), 0, stream>>>(
      att, w_outb, nullptr, nullptr, nullptr, nullptr, out, 1024, 8);
}